// Round 2
// baseline (202.289 us; speedup 1.0000x reference)
//
#include <hip/hip_runtime.h>
#include <stdint.h>

// out[r][c] = Y[r][c];  out[r][x[j]] += dt^2 * (deno @ X)[r][j]
// M = N = K = 4096, S = 64, dt^2 = 1e-6. Y/X/deno/out are FP32, x int32.
//
// v2b: fuse the fp32 copy INTO the GEMM kernel (block owns 16 rows: copies
// them, computes deno@X for them, scatters -- no cross-block hazards).
// 1024-thread blocks (16 waves, K=256 each) double occupancy vs v1, and the
// streaming copy interleaved into the K-loop supplies independent memory
// traffic to hide the MFMA-operand load latency that capped v1 at 1.25 TB/s.
// (v2 failed to compile: __builtin_nontemporal_* needs clang ext_vector types,
//  not HIP_vector_type uint4/float4.)

#define MDIM 4096
#define NDIM 4096
#define SDIM 64
#define KDIM 4096
#define WAVES 16
#define KWAVE (KDIM / WAVES)   // 256 K per wave

typedef __bf16       bf16x8 __attribute__((ext_vector_type(8)));
typedef float        f32x4  __attribute__((ext_vector_type(4)));
typedef unsigned int u32x4  __attribute__((ext_vector_type(4)));

union ABits { u32x4 u; bf16x8 v; };

// ---------- 1. XT[n][k] = bf16(X[k][n])  (XT: [64][4096] ushort) ----------
__global__ __launch_bounds__(256) void k_transpose(const float* __restrict__ X,
                                                   unsigned short* __restrict__ XT) {
    int g = blockIdx.x * 256 + threadIdx.x;   // 0 .. 64*4096-1
    int n = g >> 12;
    int k = g & (KDIM - 1);
    union { float f; unsigned int u; } c;
    c.f = X[k * SDIM + n];                    // strided read, X=1MB L1/L2-resident
    XT[g] = (unsigned short)(c.u >> 16);      // truncate to bf16
}

// ---------- 2. fused copy + GEMM (bf16 MFMA) + scatter ----------
// Block = 16 rows. 16 waves split K (256 each). Per K-iteration each lane
// also moves 2 float4 of the row-slab copy (out = Y) -- independent streaming
// traffic that keeps the memory pipe busy while MFMA operands are in flight.
// mfma_f32_16x16x32_bf16 layouts (HW-verified, guide §3):
//   A[m][k]: m = lane&15, k = (lane>>4)*8 + j
//   B[k][n]: n = lane&15, k = (lane>>4)*8 + j  (XT stored [n][k])
//   D: col = lane&15, row = (lane>>4)*4 + reg
__global__ __launch_bounds__(1024) void k_fused(
    const float* __restrict__ deno, const unsigned short* __restrict__ XT,
    const float* __restrict__ Y, const int* __restrict__ x,
    float* __restrict__ out) {

    __shared__ float red[WAVES][16 * 68];   // row stride 68 (pad: kills 4-way wr conflicts)

    const int t    = threadIdx.x;
    const int w    = t >> 6;          // 0..15
    const int lane = t & 63;
    const int r15  = lane & 15;
    const int q    = lane >> 4;
    const int m0   = blockIdx.x * 16;
    const int kw   = w * KWAVE;       // this wave's K range (256)

    const float*          ap  = deno + (size_t)(m0 + r15) * KDIM + kw + q * 8;
    const unsigned short* bp0 = XT + (size_t)(r15 +  0) * KDIM + kw + q * 8;
    const unsigned short* bp1 = XT + (size_t)(r15 + 16) * KDIM + kw + q * 8;
    const unsigned short* bp2 = XT + (size_t)(r15 + 32) * KDIM + kw + q * 8;
    const unsigned short* bp3 = XT + (size_t)(r15 + 48) * KDIM + kw + q * 8;

    // copy pointers: this block owns rows m0..m0+15 -> 16384 float4, 16/thread
    const f32x4* __restrict__ Ysrc = (const f32x4*)(Y   + (size_t)m0 * NDIM);
    f32x4*       __restrict__ Odst = (f32x4*)      (out + (size_t)m0 * NDIM);

    f32x4 acc0 = {0.f,0.f,0.f,0.f}, acc1 = {0.f,0.f,0.f,0.f};
    f32x4 acc2 = {0.f,0.f,0.f,0.f}, acc3 = {0.f,0.f,0.f,0.f};

#pragma unroll
    for (int it = 0; it < 8; ++it) {
        // A: 8 fp32 -> 8 bf16 (truncation; dt^2 scaling makes the error ~1e-6)
        u32x4 lo = __builtin_nontemporal_load((const u32x4*)(ap));
        u32x4 hi = __builtin_nontemporal_load((const u32x4*)(ap + 4));

        bf16x8 b0 = *(const bf16x8*)bp0;     // XT: keep L2-cached (shared by all blocks)
        bf16x8 b1 = *(const bf16x8*)bp1;
        bf16x8 b2 = *(const bf16x8*)bp2;
        bf16x8 b3 = *(const bf16x8*)bp3;

        // streaming copy: 2 float4 per lane per iteration (16 total)
        f32x4 c0 = __builtin_nontemporal_load(Ysrc + (t + 2048 * it));
        f32x4 c1 = __builtin_nontemporal_load(Ysrc + (t + 2048 * it + 1024));

        ABits a;
        a.u.x = (lo.y & 0xFFFF0000u) | (lo.x >> 16);
        a.u.y = (lo.w & 0xFFFF0000u) | (lo.z >> 16);
        a.u.z = (hi.y & 0xFFFF0000u) | (hi.x >> 16);
        a.u.w = (hi.w & 0xFFFF0000u) | (hi.z >> 16);

        acc0 = __builtin_amdgcn_mfma_f32_16x16x32_bf16(a.v, b0, acc0, 0, 0, 0);
        acc1 = __builtin_amdgcn_mfma_f32_16x16x32_bf16(a.v, b1, acc1, 0, 0, 0);
        acc2 = __builtin_amdgcn_mfma_f32_16x16x32_bf16(a.v, b2, acc2, 0, 0, 0);
        acc3 = __builtin_amdgcn_mfma_f32_16x16x32_bf16(a.v, b3, acc3, 0, 0, 0);

        __builtin_nontemporal_store(c0, Odst + (t + 2048 * it));
        __builtin_nontemporal_store(c1, Odst + (t + 2048 * it + 1024));

        ap += 32; bp0 += 32; bp1 += 32; bp2 += 32; bp3 += 32;
    }

    // per-wave partials to LDS (padded stride 68: <=2 lanes/bank on writes)
#pragma unroll
    for (int reg = 0; reg < 4; ++reg) {
        const int rl = q * 4 + reg;
        float* rw = &red[w][rl * 68];
        rw[ 0 + r15] = acc0[reg];
        rw[16 + r15] = acc1[reg];
        rw[32 + r15] = acc2[reg];
        rw[48 + r15] = acc3[reg];
    }
    __syncthreads();   // also drains copy stores (vmcnt(0) before s_barrier)

    // reduce 16 waves + scatter: out[r][x[c]] = Y[r][x[c]] + dt^2 * s
    // t = 0..1023 covers exactly 16 rows x 64 src cols
    const int rl = t >> 6;
    const int c  = t & 63;
    float s = 0.f;
#pragma unroll
    for (int ww = 0; ww < WAVES; ++ww) s += red[ww][rl * 68 + c];
    const size_t a = (size_t)(m0 + rl) * NDIM + x[c];
    out[a] = Y[a] + 1e-6f * s;                 // dt^2 = 1e-6
}

extern "C" void kernel_launch(void* const* d_in, const int* in_sizes, int n_in,
                              void* d_out, int out_size, void* d_ws, size_t ws_size,
                              hipStream_t stream) {
    const float* Y    = (const float*)d_in[0];
    const float* X    = (const float*)d_in[1];
    const float* deno = (const float*)d_in[2];
    const int*   x    = (const int*)d_in[3];

    unsigned short* XT = (unsigned short*)d_ws;    // 64*4096*2 B = 512 KB

    k_transpose<<<(SDIM * KDIM) / 256, 256, 0, stream>>>(X, XT);
    k_fused<<<MDIM / 16, 1024, 0, stream>>>(deno, XT, Y, x, (float*)d_out);
}